// Round 7
// baseline (35.467 us; speedup 1.0000x reference)
//
#include <hip/hip_runtime.h>
#include <math.h>

#define N_BOIDS 8192
typedef float f32x2 __attribute__((ext_vector_type(2)));
typedef float f32x4 __attribute__((ext_vector_type(4)));

constexpr int   BLOCK       = 1024;               // 16 waves
constexpr int   JSPLIT      = 2;                  // waves sharing one boid-group
constexpr int   GROUPS      = (BLOCK / 64) / JSPLIT;  // 8 groups / block
constexpr int   I_PER_GROUP = 2;                  // boids per group
constexpr int   I_PER_BLOCK = GROUPS * I_PER_GROUP;   // 16
constexpr int   TILE        = 4096;               // j-boids per LDS tile (64 KB)
constexpr int   NTILES      = N_BOIDS / TILE;     // 2
constexpr int   K_PER_WAVE  = TILE / 64 / JSPLIT; // 32 iters per tile per wave
// f32 roundings of the Python doubles 0.02**2 and 0.2**2
constexpr float SEP_R2  = 4.0000000000000008e-04f;
constexpr float PERC_R2 = 4.0000000000000001e-02f;
constexpr float EPSF    = 1e-08f;

__device__ __forceinline__ void finalize_boid(
    int i, const f32x2* __restrict__ vel, const f32x2* __restrict__ noise,
    float ws, float wa, float wc, float wn,
    float sx, float sy, float vx, float vy, float cx, float cy, float cntall,
    float* __restrict__ out)
{
    const float cnt = cntall - 1.0f;  // remove self (d2 == 0 passed the mask)

    // separation
    float ns  = fmaxf(sqrtf(sx * sx + sy * sy), EPSF);
    float ssx = sx / ns, ssy = sy / ns;

    // alignment: (sum incl. self - vi)/cnt - vi
    const f32x2 vi = vel[i];
    float vax = (vx - vi.x) / cnt - vi.x;
    float vay = (vy - vi.y) / cnt - vi.y;
    float na  = fmaxf(sqrtf(vax * vax + vay * vay), EPSF);
    float sax = vax / na, say = vay / na;

    // cohesion (self added exactly 0)
    float pax = cx / cnt, pay = cy / cnt;
    float nc  = fmaxf(sqrtf(pax * pax + pay * pay), EPSF);
    float scx = pax / nc, scy = pay / nc;

    float ax = ws * ssx + wa * sax + wc * scx;
    float ay = ws * ssy + wa * say + wc * scy;
    const f32x2 nz = noise[i];
    ax += wn * nz.x;
    ay += wn * nz.y;

    const float nn = sqrtf(ax * ax + ay * ay);
    if (nn > 1.0f) {
        const float s = 1.0f / fmaxf(nn, EPSF);
        ax *= s;
        ay *= s;
    }
    out[2 * i]     = ax;
    out[2 * i + 1] = ay;
}

__global__ __launch_bounds__(BLOCK, 8) void boids_kernel(
    const f32x2* __restrict__ pos,
    const f32x2* __restrict__ vel,
    const f32x2* __restrict__ noise,
    const float* __restrict__ w_sep,
    const float* __restrict__ w_ali,
    const float* __restrict__ w_coh,
    const float* __restrict__ w_noise,
    float* __restrict__ out)
{
    __shared__ f32x4 tile[TILE];            // (px,py,vx,vy): 64 KB
    __shared__ float comb[GROUPS][16];      // cross-wave partials: 512 B

    const int tid  = threadIdx.x;
    const int lane = tid & 63;
    const int wid  = tid >> 6;
    const int g    = wid >> 1;      // boid group 0..7
    const int h    = wid & 1;       // j-range half
    const int i0   = blockIdx.x * I_PER_BLOCK + g * I_PER_GROUP;

    const f32x2 P0 = pos[i0];
    const f32x2 P1 = pos[i0 + 1];
    const float vperc = PERC_R2;
    const float vsep  = SEP_R2;

    float n0  = 0.f, s0x = 0.f, s0y = 0.f, v0x = 0.f, v0y = 0.f, c0x = 0.f, c0y = 0.f;
    float n1  = 0.f, s1x = 0.f, s1y = 0.f, v1x = 0.f, v1y = 0.f, c1x = 0.f, c1y = 0.f;

    for (int t = 0; t < NTILES; ++t) {
        // stage TILE boids: pos+vel interleaved as (px,py,vx,vy)
        const f32x4* gp = reinterpret_cast<const f32x4*>(pos) + t * (TILE / 2);
        const f32x4* gv = reinterpret_cast<const f32x4*>(vel) + t * (TILE / 2);
#pragma unroll
        for (int c = 0; c < TILE / 2 / BLOCK; ++c) {  // 2 iters
            const int idx  = tid + c * BLOCK;
            const f32x4 pp = gp[idx];   // positions of boids 2*idx, 2*idx+1
            const f32x4 vv = gv[idx];
            f32x4 t0; t0.x = pp.x; t0.y = pp.y; t0.z = vv.x; t0.w = vv.y;
            f32x4 t1; t1.x = pp.z; t1.y = pp.w; t1.z = vv.z; t1.w = vv.w;
            tile[2 * idx]     = t0;
            tile[2 * idx + 1] = t1;
        }
        __syncthreads();

        const int kbase = h * K_PER_WAVE;
#pragma unroll 8
        for (int k = 0; k < K_PER_WAVE; ++k) {  // 32 iters
            const f32x4 q = tile[lane + (kbase + k) * 64];
            float dx0, dy0, dx1, dy1, ta, tb, tc, m;
            unsigned long long ka, kb, kc;
            asm(
                // ---- toroidal diffs + d2 for both boids (18 VALU)
                "v_sub_f32   %[dx0], %[qx], %[p0x]\n\t"
                "v_sub_f32   %[dy0], %[qy], %[p0y]\n\t"
                "v_sub_f32   %[dx1], %[qx], %[p1x]\n\t"
                "v_sub_f32   %[dy1], %[qy], %[p1y]\n\t"
                "v_rndne_f32 %[ta], %[dx0]\n\t"
                "v_rndne_f32 %[tb], %[dy0]\n\t"
                "v_sub_f32   %[dx0], %[dx0], %[ta]\n\t"
                "v_sub_f32   %[dy0], %[dy0], %[tb]\n\t"
                "v_rndne_f32 %[ta], %[dx1]\n\t"
                "v_rndne_f32 %[tb], %[dy1]\n\t"
                "v_sub_f32   %[dx1], %[dx1], %[ta]\n\t"
                "v_sub_f32   %[dy1], %[dy1], %[tb]\n\t"
                "v_mul_f32   %[ta], %[dx0], %[dx0]\n\t"
                "v_mul_f32   %[tb], %[dy0], %[dy0]\n\t"
                "v_add_f32   %[ta], %[ta], %[tb]\n\t"   // d2 boid0
                "v_mul_f32   %[tb], %[dx1], %[dx1]\n\t"
                "v_mul_f32   %[tc], %[dy1], %[dy1]\n\t"
                "v_add_f32   %[tb], %[tb], %[tc]\n\t"   // d2 boid1
                // ---- perception boid0 (7 VALU)
                "v_cmp_ge_f32 vcc, %[vperc], %[ta]\n\t"
                "v_cndmask_b32 %[m], 0, 1.0, vcc\n\t"
                "v_add_f32   %[n0], %[n0], %[m]\n\t"
                "v_fmac_f32  %[v0x], %[m], %[qz]\n\t"
                "v_fmac_f32  %[v0y], %[m], %[qw]\n\t"
                "v_fmac_f32  %[c0x], %[m], %[dx0]\n\t"
                "v_fmac_f32  %[c0y], %[m], %[dy0]\n\t"
                // ---- perception boid1 (7 VALU)
                "v_cmp_ge_f32 vcc, %[vperc], %[tb]\n\t"
                "v_cndmask_b32 %[m], 0, 1.0, vcc\n\t"
                "v_add_f32   %[n1], %[n1], %[m]\n\t"
                "v_fmac_f32  %[v1x], %[m], %[qz]\n\t"
                "v_fmac_f32  %[v1y], %[m], %[qw]\n\t"
                "v_fmac_f32  %[c1x], %[m], %[dx1]\n\t"
                "v_fmac_f32  %[c1y], %[m], %[dy1]\n\t"
                // ---- separation: uniform skip when no lane hits (~92%)
                "v_cmp_ge_f32 %[ka], %[vsep], %[ta]\n\t"
                "v_cmp_ge_f32 %[kb], %[vsep], %[tb]\n\t"
                "s_or_b64    %[kc], %[ka], %[kb]\n\t"
                "s_cbranch_scc0 Lsep%=\n\t"
                "v_cndmask_b32 %[m], 0, 1.0, %[ka]\n\t"
                "v_fma_f32   %[s0x], -%[m], %[dx0], %[s0x]\n\t"
                "v_fma_f32   %[s0y], -%[m], %[dy0], %[s0y]\n\t"
                "v_cndmask_b32 %[m], 0, 1.0, %[kb]\n\t"
                "v_fma_f32   %[s1x], -%[m], %[dx1], %[s1x]\n\t"
                "v_fma_f32   %[s1y], -%[m], %[dy1], %[s1y]\n\t"
                "Lsep%=:"
                : [dx0] "=&v"(dx0), [dy0] "=&v"(dy0),
                  [dx1] "=&v"(dx1), [dy1] "=&v"(dy1),
                  [ta] "=&v"(ta), [tb] "=&v"(tb), [tc] "=&v"(tc), [m] "=&v"(m),
                  [ka] "=&s"(ka), [kb] "=&s"(kb), [kc] "=&s"(kc),
                  [n0] "+v"(n0), [s0x] "+v"(s0x), [s0y] "+v"(s0y),
                  [v0x] "+v"(v0x), [v0y] "+v"(v0y),
                  [c0x] "+v"(c0x), [c0y] "+v"(c0y),
                  [n1] "+v"(n1), [s1x] "+v"(s1x), [s1y] "+v"(s1y),
                  [v1x] "+v"(v1x), [v1y] "+v"(v1y),
                  [c1x] "+v"(c1x), [c1y] "+v"(c1y)
                : [qx] "v"(q.x), [qy] "v"(q.y), [qz] "v"(q.z), [qw] "v"(q.w),
                  [p0x] "v"(P0.x), [p0y] "v"(P0.y),
                  [p1x] "v"(P1.x), [p1y] "v"(P1.y),
                  [vperc] "v"(vperc), [vsep] "v"(vsep)
                : "vcc", "scc");
        }
        __syncthreads();
    }

    // wave-level butterfly reduction
#pragma unroll
    for (int mlev = 1; mlev < 64; mlev <<= 1) {
        n0  += __shfl_xor(n0,  mlev);
        s0x += __shfl_xor(s0x, mlev);  s0y += __shfl_xor(s0y, mlev);
        v0x += __shfl_xor(v0x, mlev);  v0y += __shfl_xor(v0y, mlev);
        c0x += __shfl_xor(c0x, mlev);  c0y += __shfl_xor(c0y, mlev);
        n1  += __shfl_xor(n1,  mlev);
        s1x += __shfl_xor(s1x, mlev);  s1y += __shfl_xor(s1y, mlev);
        v1x += __shfl_xor(v1x, mlev);  v1y += __shfl_xor(v1y, mlev);
        c1x += __shfl_xor(c1x, mlev);  c1y += __shfl_xor(c1y, mlev);
    }

    // cross-wave combine: h==1 publishes, h==0 merges and finalizes
    if (h == 1 && lane == 0) {
        comb[g][0]  = s0x; comb[g][1]  = s0y;
        comb[g][2]  = v0x; comb[g][3]  = v0y;
        comb[g][4]  = c0x; comb[g][5]  = c0y;
        comb[g][6]  = n0;
        comb[g][7]  = s1x; comb[g][8]  = s1y;
        comb[g][9]  = v1x; comb[g][10] = v1y;
        comb[g][11] = c1x; comb[g][12] = c1y;
        comb[g][13] = n1;
    }
    __syncthreads();

    if (h == 0 && lane < I_PER_GROUP) {
        float sx = s0x, sy = s0y, vx = v0x, vy = v0y, cx = c0x, cy = c0y, cc = n0;
        if (lane == 1) {
            sx = s1x; sy = s1y; vx = v1x; vy = v1y; cx = c1x; cy = c1y; cc = n1;
        }
        const float* cb = &comb[g][lane * 7];
        sx += cb[0]; sy += cb[1]; vx += cb[2]; vy += cb[3];
        cx += cb[4]; cy += cb[5]; cc += cb[6];
        const float ws = w_sep[0], wa = w_ali[0], wc = w_coh[0], wn = w_noise[0];
        finalize_boid(i0 + lane, vel, noise, ws, wa, wc, wn,
                      sx, sy, vx, vy, cx, cy, cc, out);
    }
}

extern "C" void kernel_launch(void* const* d_in, const int* in_sizes, int n_in,
                              void* d_out, int out_size, void* d_ws, size_t ws_size,
                              hipStream_t stream) {
    const f32x2* pos     = (const f32x2*)d_in[0];
    const f32x2* vel     = (const f32x2*)d_in[1];
    const f32x2* noise   = (const f32x2*)d_in[2];
    const float* w_sep   = (const float*)d_in[3];
    const float* w_ali   = (const float*)d_in[4];
    const float* w_coh   = (const float*)d_in[5];
    const float* w_noise = (const float*)d_in[6];
    float* out = (float*)d_out;

    const int grid = N_BOIDS / I_PER_BLOCK;  // 512 blocks of 1024 threads
    boids_kernel<<<grid, BLOCK, 0, stream>>>(pos, vel, noise, w_sep, w_ali,
                                             w_coh, w_noise, out);
}